// Round 1
// baseline (1166.427 us; speedup 1.0000x reference)
//
#include <hip/hip_runtime.h>
#include <math.h>

// Problem constants
#define PVOX 110592   // 48*48*48
#define CDIM 128
#define EDIM 512

typedef __attribute__((ext_vector_type(8))) short short8_t;
typedef __attribute__((ext_vector_type(4))) float float4_t;

__device__ __forceinline__ unsigned short f2bf(float f) {
  unsigned int u = __float_as_uint(f);
  unsigned int r = (u + 0x7FFFu + ((u >> 16) & 1u)) >> 16;  // RNE
  return (unsigned short)r;
}
__device__ __forceinline__ float bf2f(unsigned short s) {
  return __uint_as_float(((unsigned int)s) << 16);
}
// XOR-swizzled bf16 tile layout: row-major stride 128, 8-elem chunks permuted.
// Keeps b128 frag reads / staging writes at the 8-phase LDS minimum.
__device__ __forceinline__ int swz(int row, int col) {
  return (row << 7) + ((((col >> 3) ^ (row & 15)) << 3) | (col & 7));
}
// fp32 output tile [c][p], stride 128, word-level XOR swizzle
__device__ __forceinline__ int swzO(int c, int p) {
  return (c << 7) + (p ^ ((c & 15) << 2));
}

// ---------------- K0: weight prep (transpose + bf16 cast) ----------------
__global__ __launch_bounds__(256) void k0_wprep(
    const float* __restrict__ w1, const float* __restrict__ w2,
    unsigned short* __restrict__ w1t, unsigned short* __restrict__ w2t) {
  int idx = blockIdx.x * 256 + threadIdx.x;  // 0..65535
  int e = idx >> 7, c = idx & 127;
  w1t[e * 128 + c] = f2bf(w1[c * 512 + e]);  // w1t[e][c]  (B^T for pw1)
  w2t[c * 512 + e] = f2bf(w2[e * 128 + c]);  // w2t[c][e]  (B^T for pw2)
}

// ---------------- K1: depthwise 7x7x7 conv + bias (NCDHW fp32) ----------------
// block: one (b, c, 4x8x48 tile). Halo staged in LDS, 6 outputs/thread along W.
__global__ __launch_bounds__(256) void k1_dwconv(
    const float* __restrict__ x, const float* __restrict__ dw_w,
    const float* __restrict__ dw_b, float* __restrict__ yconv) {
  __shared__ float sx[10 * 14 * 54];  // (4+6)x(8+6)x(48+6) halo, 29.5 KB
  __shared__ float sw[343];
  int bx = blockIdx.x;
  int ht = bx % 6;  int tmp = bx / 6;
  int dt = tmp % 12; tmp /= 12;
  int c = tmp & 127; int b = tmp >> 7;
  int d0 = dt * 4, h0 = ht * 8;
  const float* xp = x + (size_t)(b * 128 + c) * PVOX;
  int t = threadIdx.x;
  for (int i = t; i < 343; i += 256) sw[i] = dw_w[c * 343 + i];
  for (int i = t; i < 7560; i += 256) {
    int ww = i % 54; int r = i / 54; int hh = r % 14; int dd = r / 14;
    int gd = d0 - 3 + dd, gh = h0 - 3 + hh, gw = ww - 3;
    float v = 0.f;
    if ((unsigned)gd < 48u && (unsigned)gh < 48u && (unsigned)gw < 48u)
      v = xp[(gd * 48 + gh) * 48 + gw];
    sx[i] = v;
  }
  __syncthreads();
  int row = t >> 3;       // 0..31
  int chunk = t & 7;      // 0..7
  int td = row >> 3, th = row & 7;
  int w0 = chunk * 6;
  float bias = dw_b[c];
  float a0 = bias, a1 = bias, a2 = bias, a3 = bias, a4 = bias, a5 = bias;
  for (int kd = 0; kd < 7; kd++) {
    for (int kh = 0; kh < 7; kh++) {
      const float* rp = &sx[((td + kd) * 14 + (th + kh)) * 54 + w0];
      float v[12];
#pragma unroll
      for (int j = 0; j < 12; j++) v[j] = rp[j];
      const float* wp = &sw[(kd * 7 + kh) * 7];
#pragma unroll
      for (int kw = 0; kw < 7; kw++) {
        float wv = wp[kw];
        a0 += wv * v[kw + 0]; a1 += wv * v[kw + 1]; a2 += wv * v[kw + 2];
        a3 += wv * v[kw + 3]; a4 += wv * v[kw + 4]; a5 += wv * v[kw + 5];
      }
    }
  }
  float* op = yconv + (size_t)(b * 128 + c) * PVOX + ((d0 + td) * 48 + (h0 + th)) * 48 + w0;
  op[0] = a0; op[1] = a1; op[2] = a2; op[3] = a3; op[4] = a4; op[5] = a5;
}

// ---------------- K2: LayerNorm over C + transpose to channels-last bf16 ----------------
__global__ __launch_bounds__(256) void k2_ln(
    const float* __restrict__ yconv, const float* __restrict__ ln_g,
    const float* __restrict__ ln_b, unsigned short* __restrict__ ycl) {
  __shared__ float sy[128 * 65];  // stride 65 breaks bank conflicts
  __shared__ float smean[64], srstd[64];
  int bx = blockIdx.x;
  int b = bx / 1728;
  int p0 = (bx % 1728) * 64;
  int t = threadIdx.x;
  int v = t & 63, c4 = t >> 6;
  const float* yp = yconv + (size_t)b * 128 * PVOX + p0;
  for (int cc = 0; cc < 32; cc++) {
    int c = cc * 4 + c4;
    sy[c * 65 + v] = yp[(size_t)c * PVOX + v];
  }
  __syncthreads();
  if (t < 64) {
    float s = 0.f, ss = 0.f;
    for (int c = 0; c < 128; c++) { float val = sy[c * 65 + t]; s += val; ss += val * val; }
    float mu = s * (1.f / 128.f);
    float var = ss * (1.f / 128.f) - mu * mu;
    smean[t] = mu; srstd[t] = rsqrtf(var + 1e-6f);
  }
  __syncthreads();
  unsigned short* op = ycl + ((size_t)b * PVOX + p0) * 128;
  for (int it = 0; it < 32; it++) {
    int idx = it * 256 + t;
    int vv = idx >> 7, c = idx & 127;
    float val = (sy[c * 65 + vv] - smean[vv]) * srstd[vv] * ln_g[c] + ln_b[c];
    op[vv * 128 + c] = f2bf(val);
  }
}

// ---------------- K3: pwconv1 (bf16 MFMA) + bias + GELU + GRN sumsq ----------------
// grid: 1728 p-tiles x 4 e-tiles. Block tile 128p x 128e, K=128, 4 waves of 64x64.
__global__ __launch_bounds__(256) void k3_pw1(
    const unsigned short* __restrict__ ycl, const unsigned short* __restrict__ w1t,
    const float* __restrict__ b1, unsigned short* __restrict__ h,
    float* __restrict__ gsum) {
  __shared__ short smem[2 * 128 * 128];  // 64 KB
  short* sA = smem;
  short* sB = smem + 128 * 128;
  int bx = blockIdx.x;
  int et = bx & 3; int pt = bx >> 2;   // pt 0..1727
  int e0 = et << 7;
  int b = (pt >= 864) ? 1 : 0;
  int t = threadIdx.x;
  // stage A (y tile) and B (w1t tile), swizzled
  for (int it = 0; it < 8; it++) {
    int flat = it * 2048 + t * 8;
    int row = flat >> 7, col = flat & 127;
    *(uint4*)&sA[swz(row, col)] = *(const uint4*)&ycl[((size_t)(pt * 128 + row)) * 128 + col];
    *(uint4*)&sB[swz(row, col)] = *(const uint4*)&w1t[(e0 + row) * 128 + col];
  }
  __syncthreads();
  int wave = t >> 6, lane = t & 63;
  int wm = (wave >> 1) * 64, wn = (wave & 1) * 64;
  int ln15 = lane & 15, q = lane >> 4;
  float4_t acc[4][4] = {};
  for (int kk = 0; kk < 4; kk++) {
    int k0 = kk * 32 + q * 8;
    short8_t af[4], bf[4];
#pragma unroll
    for (int i = 0; i < 4; i++)
      af[i] = *(const short8_t*)&sA[swz(wm + i * 16 + ln15, k0)];
#pragma unroll
    for (int j = 0; j < 4; j++)
      bf[j] = *(const short8_t*)&sB[swz(wn + j * 16 + ln15, k0)];
#pragma unroll
    for (int i = 0; i < 4; i++)
#pragma unroll
      for (int j = 0; j < 4; j++)
        acc[i][j] = __builtin_amdgcn_mfma_f32_16x16x32_bf16(af[i], bf[j], acc[i][j], 0, 0, 0);
  }
  __syncthreads();  // done reading A/B; reuse sA for h restage
  float biasv[4];
#pragma unroll
  for (int j = 0; j < 4; j++) biasv[j] = b1[e0 + wn + j * 16 + ln15];
  float ssq[4] = {0.f, 0.f, 0.f, 0.f};
#pragma unroll
  for (int i = 0; i < 4; i++) {
#pragma unroll
    for (int j = 0; j < 4; j++) {
      int e_local = wn + j * 16 + ln15;
#pragma unroll
      for (int r = 0; r < 4; r++) {
        float val = acc[i][j][r] + biasv[j];
        float g = 0.5f * val * (1.0f + erff(val * 0.70710678118f));
        ssq[j] += g * g;
        sA[swz(wm + i * 16 + q * 4 + r, e_local)] = (short)f2bf(g);
      }
    }
  }
  // reduce sumsq over the 4 quads (rows) of this wave, then atomic per e
#pragma unroll
  for (int j = 0; j < 4; j++) {
    ssq[j] += __shfl_xor(ssq[j], 16);
    ssq[j] += __shfl_xor(ssq[j], 32);
  }
  if (q == 0) {
#pragma unroll
    for (int j = 0; j < 4; j++)
      atomicAdd(&gsum[b * 512 + e0 + wn + j * 16 + ln15], ssq[j]);
  }
  __syncthreads();
  // coalesced h write
  for (int it = 0; it < 8; it++) {
    int flat = it * 2048 + t * 8;
    int row = flat >> 7, col = flat & 127;
    *(uint4*)&h[((size_t)(pt * 128 + row)) * 512 + e0 + col] = *(const uint4*)&sA[swz(row, col)];
  }
}

// ---------------- K4: GRN scalars: s[b,e] = 1 + grn_g*nx ; badd[c] = b2 + grn_b @ w2 ----------------
__global__ __launch_bounds__(512) void k4_grn(
    const float* __restrict__ gsum, const float* __restrict__ grn_g,
    const float* __restrict__ grn_b, const float* __restrict__ w2,
    const float* __restrict__ b2, float* __restrict__ s, float* __restrict__ badd) {
  __shared__ float red[512];
  int t = threadIdx.x;
  for (int b = 0; b < 2; b++) {
    float gx = sqrtf(gsum[b * 512 + t]);
    red[t] = gx;
    __syncthreads();
    for (int off = 256; off > 0; off >>= 1) {
      if (t < off) red[t] += red[t + off];
      __syncthreads();
    }
    float mean = red[0] * (1.f / 512.f);
    __syncthreads();
    s[b * 512 + t] = 1.0f + grn_g[t] * (gx / (mean + 1e-6f));
  }
  if (t < 128) {
    float acc = b2[t];
    for (int e = 0; e < 512; e++) acc += grn_b[e] * w2[e * 128 + t];
    badd[t] = acc;
  }
}

// ---------------- K5: pwconv2 (bf16 MFMA, K=512) + badd + residual, NCDHW out ----------------
__global__ __launch_bounds__(256) void k5_pw2(
    const unsigned short* __restrict__ h, const unsigned short* __restrict__ w2t,
    const float* __restrict__ s, const float* __restrict__ badd,
    const float* __restrict__ x, float* __restrict__ out) {
  __shared__ short smem[2 * 128 * 128];  // 64 KB; reused as fp32 out-tile at end
  short* sA = smem;
  short* sB = smem + 128 * 128;
  int bx = blockIdx.x;           // 0..1727
  int b = bx / 864;
  int p0 = (bx % 864) * 128;     // within-batch voxel base
  int vp0 = bx * 128;            // global voxel base
  int t = threadIdx.x;
  int wave = t >> 6, lane = t & 63;
  int wm = (wave >> 1) * 64, wn = (wave & 1) * 64;
  int ln15 = lane & 15, q = lane >> 4;
  const float* sb = s + b * 512;
  float4_t acc[4][4] = {};
  for (int ec = 0; ec < 4; ec++) {
    int e0 = ec * 128;
    for (int it = 0; it < 8; it++) {
      int flat = it * 2048 + t * 8;
      int row = flat >> 7, col = flat & 127;
      uint4 raw = *(const uint4*)&h[((size_t)(vp0 + row)) * 512 + e0 + col];
      const unsigned short* us = (const unsigned short*)&raw;
      unsigned short ov[8];
#pragma unroll
      for (int i2 = 0; i2 < 8; i2++)
        ov[i2] = f2bf(bf2f(us[i2]) * sb[e0 + col + i2]);
      *(uint4*)&sA[swz(row, col)] = *(const uint4*)ov;
      *(uint4*)&sB[swz(row, col)] = *(const uint4*)&w2t[row * 512 + e0 + col];  // row = c
    }
    __syncthreads();
    for (int kk = 0; kk < 4; kk++) {
      int k0 = kk * 32 + q * 8;
      short8_t af[4], bf[4];
#pragma unroll
      for (int i = 0; i < 4; i++)
        af[i] = *(const short8_t*)&sA[swz(wm + i * 16 + ln15, k0)];
#pragma unroll
      for (int j = 0; j < 4; j++)
        bf[j] = *(const short8_t*)&sB[swz(wn + j * 16 + ln15, k0)];
#pragma unroll
      for (int i = 0; i < 4; i++)
#pragma unroll
        for (int j = 0; j < 4; j++)
          acc[i][j] = __builtin_amdgcn_mfma_f32_16x16x32_bf16(af[i], bf[j], acc[i][j], 0, 0, 0);
    }
    __syncthreads();
  }
  // restage out-tile to LDS as fp32 [c][p] for coalesced NCDHW writes
  float* sO = (float*)smem;
#pragma unroll
  for (int i = 0; i < 4; i++)
#pragma unroll
    for (int j = 0; j < 4; j++) {
      int c = wn + j * 16 + ln15;
#pragma unroll
      for (int r = 0; r < 4; r++)
        sO[swzO(c, wm + i * 16 + q * 4 + r)] = acc[i][j][r];
    }
  __syncthreads();
  for (int it = 0; it < 16; it++) {
    int flat4 = it * 256 + t;          // 4096 float4s
    int c = flat4 >> 5, col4 = (flat4 & 31) * 4;
    float4_t v = *(const float4_t*)&sO[swzO(c, col4)];
    float bd = badd[c];
    size_t gi = (size_t)(b * 128 + c) * PVOX + p0 + col4;
    float4_t xv = *(const float4_t*)&x[gi];
    v[0] += bd + xv[0]; v[1] += bd + xv[1]; v[2] += bd + xv[2]; v[3] += bd + xv[3];
    *(float4_t*)&out[gi] = v;
  }
}

// ---------------- launch ----------------
extern "C" void kernel_launch(void* const* d_in, const int* in_sizes, int n_in,
                              void* d_out, int out_size, void* d_ws, size_t ws_size,
                              hipStream_t stream) {
  (void)in_sizes; (void)n_in; (void)out_size; (void)ws_size;
  const float* x    = (const float*)d_in[0];
  const float* dw_w = (const float*)d_in[1];
  const float* dw_b = (const float*)d_in[2];
  const float* ln_g = (const float*)d_in[3];
  const float* ln_b = (const float*)d_in[4];
  const float* w1   = (const float*)d_in[5];
  const float* b1   = (const float*)d_in[6];
  const float* grn_g= (const float*)d_in[7];
  const float* grn_b= (const float*)d_in[8];
  const float* w2   = (const float*)d_in[9];
  const float* b2   = (const float*)d_in[10];
  float* outp = (float*)d_out;

  char* w = (char*)d_ws;
  // ws layout (bytes): yconv fp32 113.2MB | ycl bf16 56.6MB | h bf16 226.5MB | gsum|s|badd|w1t|w2t
  float*          yconv = (float*)(w);
  unsigned short* ycl   = (unsigned short*)(w + 113246208);
  unsigned short* h     = (unsigned short*)(w + 169869312);
  float*          gsum  = (float*)(w + 396361728);
  float*          s     = (float*)(w + 396365824);
  float*          badd  = (float*)(w + 396369920);
  unsigned short* w1t   = (unsigned short*)(w + 396370432);
  unsigned short* w2t   = (unsigned short*)(w + 396501504);

  hipMemsetAsync(gsum, 0, 2 * 512 * sizeof(float), stream);
  k0_wprep<<<256, 256, 0, stream>>>(w1, w2, w1t, w2t);
  k1_dwconv<<<18432, 256, 0, stream>>>(x, dw_w, dw_b, yconv);
  k2_ln<<<3456, 256, 0, stream>>>(yconv, ln_g, ln_b, ycl);
  k3_pw1<<<6912, 256, 0, stream>>>(ycl, w1t, b1, h, gsum);
  k4_grn<<<1, 512, 0, stream>>>(gsum, grn_g, grn_b, w2, b2, s, badd);
  k5_pw2<<<1728, 256, 0, stream>>>(h, w2t, s, badd, x, outp);
}

// Round 2
// 1021.069 us; speedup vs baseline: 1.1424x; 1.1424x over previous
//
#include <hip/hip_runtime.h>
#include <math.h>

// Problem constants
#define PVOX 110592   // 48*48*48
#define CDIM 128
#define EDIM 512

typedef __attribute__((ext_vector_type(8))) short short8_t;
typedef __attribute__((ext_vector_type(4))) float float4_t;

__device__ __forceinline__ unsigned short f2bf(float f) {
  unsigned int u = __float_as_uint(f);
  unsigned int r = (u + 0x7FFFu + ((u >> 16) & 1u)) >> 16;  // RNE
  return (unsigned short)r;
}
__device__ __forceinline__ float bf2f(unsigned short s) {
  return __uint_as_float(((unsigned int)s) << 16);
}
// XOR-swizzled bf16 tile layout: row-major stride 128, 8-elem chunks permuted.
__device__ __forceinline__ int swz(int row, int col) {
  return (row << 7) + ((((col >> 3) ^ (row & 15)) << 3) | (col & 7));
}
// fp32 output tile [c][p], stride 128, word-level XOR swizzle
__device__ __forceinline__ int swzO(int c, int p) {
  return (c << 7) + (p ^ ((c & 15) << 2));
}

// ---------------- K0: weight prep (transpose + bf16 cast) ----------------
__global__ __launch_bounds__(256) void k0_wprep(
    const float* __restrict__ w1, const float* __restrict__ w2,
    unsigned short* __restrict__ w1t, unsigned short* __restrict__ w2t) {
  int idx = blockIdx.x * 256 + threadIdx.x;  // 0..65535
  int e = idx >> 7, c = idx & 127;
  w1t[e * 128 + c] = f2bf(w1[c * 512 + e]);  // w1t[e][c]  (B^T for pw1)
  w2t[c * 512 + e] = f2bf(w2[e * 128 + c]);  // w2t[c][e]  (B^T for pw2)
}

// ---------------- K1: depthwise 7x7x7 conv + bias (NCDHW fp32) ----------------
// Register-blocked rewrite: block = one (b, c, 16d x 8h x 48w tile), 384 threads.
// Each thread: 2 d x 8 w outputs. LDS halo tile row-stride 60 words (240B,
// 16B-aligned; 60 mod 32 = 28 -> b128 reads hit all 32 banks uniformly: no
// excess conflicts). Weights fetched via uniform index -> scalar loads.
__global__ __launch_bounds__(384) void k1_dwconv(
    const float* __restrict__ x, const float* __restrict__ dw_w,
    const float* __restrict__ dw_b, float* __restrict__ yconv) {
  __shared__ float sx[22 * 14 * 60];  // 72.2 KB: d-halo 22, h-halo 14, w 60 (pad 4 left)
  int bx = blockIdx.x;
  int ht = bx % 6;  int tmp = bx / 6;
  int dtile = tmp % 3; tmp /= 3;
  int c = tmp & 127; int b = tmp >> 7;
  int d0 = dtile * 16, h0 = ht * 8;
  const float* xp = x + (size_t)(b * 128 + c) * PVOX;
  int t = threadIdx.x;
  // staging: 22x14 rows x 14 granules of float4. Granule gi covers gw = gi*4-4..gi*4-1.
  // gi 1..12 fully valid (w 0..47), gi 0 and 13 fully OOB -> zero.
  for (int i = t; i < 4312; i += 384) {
    int gi = i % 14; int rr = i / 14; int hh = rr % 14; int r = rr / 14;
    int gd = d0 - 3 + r, gh = h0 - 3 + hh;
    float4_t v = {0.f, 0.f, 0.f, 0.f};
    if ((unsigned)gd < 48u && (unsigned)gh < 48u && gi >= 1 && gi <= 12)
      v = *(const float4_t*)&xp[(gd * 48 + gh) * 48 + gi * 4 - 4];
    *(float4_t*)&sx[r * 840 + hh * 60 + gi * 4] = v;
  }
  __syncthreads();
  int wc = t % 6; int h = (t / 6) % 8; int dt = t / 48;  // 6 x 8 x 8 = 384
  int w0 = wc * 8;
  const float* wbase = dw_w + c * 343;   // uniform -> s_load
  float bias = dw_b[c];
  float a0[8], a1[8];
#pragma unroll
  for (int i = 0; i < 8; i++) { a0[i] = bias; a1[i] = bias; }
  for (int kh = 0; kh < 7; kh++) {
    int hl = h + kh;
    const float* hp = &sx[hl * 60 + w0];
#pragma unroll
    for (int r8 = 0; r8 < 8; r8++) {
      int r = 2 * dt + r8;
      const float* rp = &hp[r * 840];
      float4_t v4[4];
#pragma unroll
      for (int g = 0; g < 4; g++) v4[g] = *(const float4_t*)&rp[g * 4];
      // d_local = 0 uses kd = r8 (valid r8<=6); d_local = 1 uses kd = r8-1 (valid r8>=1)
      if (r8 <= 6) {
        const float* wr = wbase + r8 * 49 + kh * 7;
#pragma unroll
        for (int kw = 0; kw < 7; kw++) {
          float wv = wr[kw];
#pragma unroll
          for (int wi = 0; wi < 8; wi++) {
            int vi = wi + kw + 1;
            a0[wi] += wv * v4[vi >> 2][vi & 3];
          }
        }
      }
      if (r8 >= 1) {
        const float* wr = wbase + (r8 - 1) * 49 + kh * 7;
#pragma unroll
        for (int kw = 0; kw < 7; kw++) {
          float wv = wr[kw];
#pragma unroll
          for (int wi = 0; wi < 8; wi++) {
            int vi = wi + kw + 1;
            a1[wi] += wv * v4[vi >> 2][vi & 3];
          }
        }
      }
    }
  }
  int dg = d0 + 2 * dt;
  float* op0 = yconv + (size_t)(b * 128 + c) * PVOX + ((size_t)dg * 48 + (h0 + h)) * 48 + w0;
  float* op1 = op0 + 48 * 48;
  float4_t o;
  o[0] = a0[0]; o[1] = a0[1]; o[2] = a0[2]; o[3] = a0[3]; *(float4_t*)&op0[0] = o;
  o[0] = a0[4]; o[1] = a0[5]; o[2] = a0[6]; o[3] = a0[7]; *(float4_t*)&op0[4] = o;
  o[0] = a1[0]; o[1] = a1[1]; o[2] = a1[2]; o[3] = a1[3]; *(float4_t*)&op1[0] = o;
  o[0] = a1[4]; o[1] = a1[5]; o[2] = a1[6]; o[3] = a1[7]; *(float4_t*)&op1[4] = o;
}

// ---------------- K2: LayerNorm over C + transpose to channels-last bf16 ----------------
__global__ __launch_bounds__(256) void k2_ln(
    const float* __restrict__ yconv, const float* __restrict__ ln_g,
    const float* __restrict__ ln_b, unsigned short* __restrict__ ycl) {
  __shared__ float sy[128 * 65];  // stride 65 breaks bank conflicts
  __shared__ float smean[64], srstd[64];
  int bx = blockIdx.x;
  int b = bx / 1728;
  int p0 = (bx % 1728) * 64;
  int t = threadIdx.x;
  int v = t & 63, c4 = t >> 6;
  const float* yp = yconv + (size_t)b * 128 * PVOX + p0;
  for (int cc = 0; cc < 32; cc++) {
    int c = cc * 4 + c4;
    sy[c * 65 + v] = yp[(size_t)c * PVOX + v];
  }
  __syncthreads();
  if (t < 64) {
    float s = 0.f, ss = 0.f;
    for (int c = 0; c < 128; c++) { float val = sy[c * 65 + t]; s += val; ss += val * val; }
    float mu = s * (1.f / 128.f);
    float var = ss * (1.f / 128.f) - mu * mu;
    smean[t] = mu; srstd[t] = rsqrtf(var + 1e-6f);
  }
  __syncthreads();
  unsigned short* op = ycl + ((size_t)b * PVOX + p0) * 128;
  for (int it = 0; it < 32; it++) {
    int idx = it * 256 + t;
    int vv = idx >> 7, c = idx & 127;
    float val = (sy[c * 65 + vv] - smean[vv]) * srstd[vv] * ln_g[c] + ln_b[c];
    op[vv * 128 + c] = f2bf(val);
  }
}

// ---------------- K3: pwconv1 (bf16 MFMA) + bias + GELU + GRN sumsq ----------------
__global__ __launch_bounds__(256) void k3_pw1(
    const unsigned short* __restrict__ ycl, const unsigned short* __restrict__ w1t,
    const float* __restrict__ b1, unsigned short* __restrict__ h,
    float* __restrict__ gsum) {
  __shared__ short smem[2 * 128 * 128];  // 64 KB
  short* sA = smem;
  short* sB = smem + 128 * 128;
  int bx = blockIdx.x;
  int et = bx & 3; int pt = bx >> 2;   // pt 0..1727
  int e0 = et << 7;
  int b = (pt >= 864) ? 1 : 0;
  int t = threadIdx.x;
  for (int it = 0; it < 8; it++) {
    int flat = it * 2048 + t * 8;
    int row = flat >> 7, col = flat & 127;
    *(uint4*)&sA[swz(row, col)] = *(const uint4*)&ycl[((size_t)(pt * 128 + row)) * 128 + col];
    *(uint4*)&sB[swz(row, col)] = *(const uint4*)&w1t[(e0 + row) * 128 + col];
  }
  __syncthreads();
  int wave = t >> 6, lane = t & 63;
  int wm = (wave >> 1) * 64, wn = (wave & 1) * 64;
  int ln15 = lane & 15, q = lane >> 4;
  float4_t acc[4][4] = {};
  for (int kk = 0; kk < 4; kk++) {
    int k0 = kk * 32 + q * 8;
    short8_t af[4], bf[4];
#pragma unroll
    for (int i = 0; i < 4; i++)
      af[i] = *(const short8_t*)&sA[swz(wm + i * 16 + ln15, k0)];
#pragma unroll
    for (int j = 0; j < 4; j++)
      bf[j] = *(const short8_t*)&sB[swz(wn + j * 16 + ln15, k0)];
#pragma unroll
    for (int i = 0; i < 4; i++)
#pragma unroll
      for (int j = 0; j < 4; j++)
        acc[i][j] = __builtin_amdgcn_mfma_f32_16x16x32_bf16(af[i], bf[j], acc[i][j], 0, 0, 0);
  }
  __syncthreads();  // done reading A/B; reuse sA for h restage
  float biasv[4];
#pragma unroll
  for (int j = 0; j < 4; j++) biasv[j] = b1[e0 + wn + j * 16 + ln15];
  float ssq[4] = {0.f, 0.f, 0.f, 0.f};
#pragma unroll
  for (int i = 0; i < 4; i++) {
#pragma unroll
    for (int j = 0; j < 4; j++) {
      int e_local = wn + j * 16 + ln15;
#pragma unroll
      for (int r = 0; r < 4; r++) {
        float val = acc[i][j][r] + biasv[j];
        float g = 0.5f * val * (1.0f + erff(val * 0.70710678118f));
        ssq[j] += g * g;
        sA[swz(wm + i * 16 + q * 4 + r, e_local)] = (short)f2bf(g);
      }
    }
  }
#pragma unroll
  for (int j = 0; j < 4; j++) {
    ssq[j] += __shfl_xor(ssq[j], 16);
    ssq[j] += __shfl_xor(ssq[j], 32);
  }
  if (q == 0) {
#pragma unroll
    for (int j = 0; j < 4; j++)
      atomicAdd(&gsum[b * 512 + e0 + wn + j * 16 + ln15], ssq[j]);
  }
  __syncthreads();
  for (int it = 0; it < 8; it++) {
    int flat = it * 2048 + t * 8;
    int row = flat >> 7, col = flat & 127;
    *(uint4*)&h[((size_t)(pt * 128 + row)) * 512 + e0 + col] = *(const uint4*)&sA[swz(row, col)];
  }
}

// ---------------- K4: GRN scalars ----------------
__global__ __launch_bounds__(512) void k4_grn(
    const float* __restrict__ gsum, const float* __restrict__ grn_g,
    const float* __restrict__ grn_b, const float* __restrict__ w2,
    const float* __restrict__ b2, float* __restrict__ s, float* __restrict__ badd) {
  __shared__ float red[512];
  int t = threadIdx.x;
  for (int b = 0; b < 2; b++) {
    float gx = sqrtf(gsum[b * 512 + t]);
    red[t] = gx;
    __syncthreads();
    for (int off = 256; off > 0; off >>= 1) {
      if (t < off) red[t] += red[t + off];
      __syncthreads();
    }
    float mean = red[0] * (1.f / 512.f);
    __syncthreads();
    s[b * 512 + t] = 1.0f + grn_g[t] * (gx / (mean + 1e-6f));
  }
  if (t < 128) {
    float acc = b2[t];
    for (int e = 0; e < 512; e++) acc += grn_b[e] * w2[e * 128 + t];
    badd[t] = acc;
  }
}

// ---------------- K5: pwconv2 (bf16 MFMA, K=512) + badd + residual ----------------
__global__ __launch_bounds__(256) void k5_pw2(
    const unsigned short* __restrict__ h, const unsigned short* __restrict__ w2t,
    const float* __restrict__ s, const float* __restrict__ badd,
    const float* __restrict__ x, float* __restrict__ out) {
  __shared__ short smem[2 * 128 * 128];  // 64 KB; reused as fp32 out-tile at end
  short* sA = smem;
  short* sB = smem + 128 * 128;
  int bx = blockIdx.x;           // 0..1727
  int b = bx / 864;
  int p0 = (bx % 864) * 128;
  int vp0 = bx * 128;
  int t = threadIdx.x;
  int wave = t >> 6, lane = t & 63;
  int wm = (wave >> 1) * 64, wn = (wave & 1) * 64;
  int ln15 = lane & 15, q = lane >> 4;
  const float* sb = s + b * 512;
  float4_t acc[4][4] = {};
  for (int ec = 0; ec < 4; ec++) {
    int e0 = ec * 128;
    for (int it = 0; it < 8; it++) {
      int flat = it * 2048 + t * 8;
      int row = flat >> 7, col = flat & 127;
      uint4 raw = *(const uint4*)&h[((size_t)(vp0 + row)) * 512 + e0 + col];
      const unsigned short* us = (const unsigned short*)&raw;
      unsigned short ov[8];
#pragma unroll
      for (int i2 = 0; i2 < 8; i2++)
        ov[i2] = f2bf(bf2f(us[i2]) * sb[e0 + col + i2]);
      *(uint4*)&sA[swz(row, col)] = *(const uint4*)ov;
      *(uint4*)&sB[swz(row, col)] = *(const uint4*)&w2t[row * 512 + e0 + col];  // row = c
    }
    __syncthreads();
    for (int kk = 0; kk < 4; kk++) {
      int k0 = kk * 32 + q * 8;
      short8_t af[4], bf[4];
#pragma unroll
      for (int i = 0; i < 4; i++)
        af[i] = *(const short8_t*)&sA[swz(wm + i * 16 + ln15, k0)];
#pragma unroll
      for (int j = 0; j < 4; j++)
        bf[j] = *(const short8_t*)&sB[swz(wn + j * 16 + ln15, k0)];
#pragma unroll
      for (int i = 0; i < 4; i++)
#pragma unroll
        for (int j = 0; j < 4; j++)
          acc[i][j] = __builtin_amdgcn_mfma_f32_16x16x32_bf16(af[i], bf[j], acc[i][j], 0, 0, 0);
    }
    __syncthreads();
  }
  float* sO = (float*)smem;
#pragma unroll
  for (int i = 0; i < 4; i++)
#pragma unroll
    for (int j = 0; j < 4; j++) {
      int c = wn + j * 16 + ln15;
#pragma unroll
      for (int r = 0; r < 4; r++)
        sO[swzO(c, wm + i * 16 + q * 4 + r)] = acc[i][j][r];
    }
  __syncthreads();
  for (int it = 0; it < 16; it++) {
    int flat4 = it * 256 + t;
    int c = flat4 >> 5, col4 = (flat4 & 31) * 4;
    float4_t v = *(const float4_t*)&sO[swzO(c, col4)];
    float bd = badd[c];
    size_t gi = (size_t)(b * 128 + c) * PVOX + p0 + col4;
    float4_t xv = *(const float4_t*)&x[gi];
    v[0] += bd + xv[0]; v[1] += bd + xv[1]; v[2] += bd + xv[2]; v[3] += bd + xv[3];
    *(float4_t*)&out[gi] = v;
  }
}

// ---------------- launch ----------------
extern "C" void kernel_launch(void* const* d_in, const int* in_sizes, int n_in,
                              void* d_out, int out_size, void* d_ws, size_t ws_size,
                              hipStream_t stream) {
  (void)in_sizes; (void)n_in; (void)out_size; (void)ws_size;
  const float* x    = (const float*)d_in[0];
  const float* dw_w = (const float*)d_in[1];
  const float* dw_b = (const float*)d_in[2];
  const float* ln_g = (const float*)d_in[3];
  const float* ln_b = (const float*)d_in[4];
  const float* w1   = (const float*)d_in[5];
  const float* b1   = (const float*)d_in[6];
  const float* grn_g= (const float*)d_in[7];
  const float* grn_b= (const float*)d_in[8];
  const float* w2   = (const float*)d_in[9];
  const float* b2   = (const float*)d_in[10];
  float* outp = (float*)d_out;

  char* w = (char*)d_ws;
  float*          yconv = (float*)(w);
  unsigned short* ycl   = (unsigned short*)(w + 113246208);
  unsigned short* h     = (unsigned short*)(w + 169869312);
  float*          gsum  = (float*)(w + 396361728);
  float*          s     = (float*)(w + 396365824);
  float*          badd  = (float*)(w + 396369920);
  unsigned short* w1t   = (unsigned short*)(w + 396370432);
  unsigned short* w2t   = (unsigned short*)(w + 396501504);

  hipMemsetAsync(gsum, 0, 2 * 512 * sizeof(float), stream);
  k0_wprep<<<256, 256, 0, stream>>>(w1, w2, w1t, w2t);
  k1_dwconv<<<4608, 384, 0, stream>>>(x, dw_w, dw_b, yconv);
  k2_ln<<<3456, 256, 0, stream>>>(yconv, ln_g, ln_b, ycl);
  k3_pw1<<<6912, 256, 0, stream>>>(ycl, w1t, b1, h, gsum);
  k4_grn<<<1, 512, 0, stream>>>(gsum, grn_g, grn_b, w2, b2, s, badd);
  k5_pw2<<<1728, 256, 0, stream>>>(h, w2t, s, badd, x, outp);
}